// Round 6
// baseline (292.296 us; speedup 1.0000x reference)
//
#include <hip/hip_runtime.h>
#include <hip/hip_bf16.h>
#include <math.h>

// ConvNeXt MLP + parallel MoE-LoRA, fp32 in/out, bf16-tolerance harness.
// B,H,W,C = 64,14,14,768 ; N_tok = 12544 = 98*128 ; HID = 3072 ; E=8,K=2,R=16.
//
//   h  = gelu(x @ w1 + b1)                GEMM1  [12544,768]x[768,3072]
//   sd = wt * gelu(x @ wdown)             GEMMd  [12544,768]x[768,128]
//   out = [h | sd] @ [w2 ; wup] + b2      GEMM2  [12544,3200]x[3200,768]
//
// R18: R17 post-mortem: 2 blocks/CU worked (32% MfmaUtil) but the 64x48 wave
// tile is LDS-read-bound: ratio M*N/(M+N) = 27.4 FLOP/B -> LDS 2636 cyc vs
// MFMA 1864 cyc per CU per k-tile (cap 71%). Fix: BK=32 halves LDS so big
// wave tiles fit multi-block:
//   GEMM1: 128x192, 4 waves, wave 64x96 (38.4 FLOP/B), 40KB -> 3 blocks/CU.
//   GEMM2: 128x128, 4 waves, wave 64x64, 32KB -> 4 blocks/CU (588 blocks all
//          resident, fine balance).
// 64B LDS rows need a NEW swizzle (3-bit one was for 128B rows): 2-bit XOR
// byte ^= ((byte>>7)&3)<<4 -> lanes (r,q) land at bank-group 4(r&1)+
// (q^((r>>1)&3)), all-distinct per 8-lane cohort (model consistent with
// R14/R15 measurements). Both-sides involution (pre-swizzled global source,
// swizzled ds_read). Same 4-phase counted-vmcnt skeleton as R17 (hazards
// re-verified: every buffer overwrite is >=1 barrier after its last reader;
// vmcnt(BCH) tails keep only the newest B-tile outstanding, never 0).

#define NTOK   12544
#define CDIM   768
#define HIDDIM 3072
#define KBIG   3200

typedef __attribute__((ext_vector_type(8))) short bf16x8;
typedef __attribute__((ext_vector_type(4))) float f32x4;

#define GLOBAL_AS(p) ((const __attribute__((address_space(1))) void*)(p))
#define LDS_AS(p)    ((__attribute__((address_space(3))) void*)(p))
#define GLD(src, dst) __builtin_amdgcn_global_load_lds(GLOBAL_AS(src), LDS_AS(dst), 16, 0, 0)

__device__ inline unsigned short f2bf(float f) {
    unsigned int x = __float_as_uint(f);
    x += 0x7fffu + ((x >> 16) & 1u);   // RNE
    return (unsigned short)(x >> 16);
}

// tanh-form GELU, branch-free; max |err| ~4.3e-4 vs exact erf form.
__device__ inline float gelu_fast(float x) {
    float x3 = x * x * x;
    float u2 = 1.5957691216057308f * x + 0.07135481627260025f * x3;
    float e = __expf(-u2);
    return x * __builtin_amdgcn_rcpf(1.0f + e);
}

// ---------------- fused prep: cast_x + 3 transposes (64x64) + pack_wdown -------
__global__ void __launch_bounds__(256) prep_kernel(
        const float* __restrict__ x, const float* __restrict__ w1,
        const float* __restrict__ w2, const float* __restrict__ wup,
        const float* __restrict__ wdn,
        unsigned short* __restrict__ xb, unsigned short* __restrict__ w1t,
        unsigned short* __restrict__ B2t, unsigned short* __restrict__ wdt) {
    __shared__ float tile[64][65];
    const int b = blockIdx.x, tid = threadIdx.x;
    if (b < 9408) {                      // cast x -> bf16, float4->ushort4
        int i = b * 256 + tid;
        float4 v = ((const float4*)x)[i];
        ushort4 o;
        o.x = f2bf(v.x); o.y = f2bf(v.y); o.z = f2bf(v.z); o.w = f2bf(v.w);
        ((ushort4*)xb)[i] = o;
        return;
    }
    if (b < 10584) {                     // 64x64 transpose tiles
        const float* in; unsigned short* outp; int Ccols, out_ld, out_off, bx, by;
        if (b < 9984)       { int t = b - 9408;  in = w1;  outp = w1t; Ccols = 3072; out_ld = 768;  out_off = 0;    bx = t % 48; by = t / 48; }
        else if (b < 10560) { int t = b - 9984;  in = w2;  outp = B2t; Ccols = 768;  out_ld = 3200; out_off = 0;    bx = t % 12; by = t / 12; }
        else                { int t = b - 10560; in = wup; outp = B2t; Ccols = 768;  out_ld = 3200; out_off = 3072; bx = t % 12; by = t / 12; }
        const int c0 = bx * 64, r0 = by * 64;
        #pragma unroll
        for (int p = 0; p < 4; ++p) {
            int idx = p * 256 + tid;
            int r = idx >> 4, c4 = (idx & 15) * 4;
            float4 v = *(const float4*)&in[(size_t)(r0 + r) * Ccols + c0 + c4];
            tile[r][c4 + 0] = v.x; tile[r][c4 + 1] = v.y;
            tile[r][c4 + 2] = v.z; tile[r][c4 + 3] = v.w;
        }
        __syncthreads();
        #pragma unroll
        for (int p = 0; p < 2; ++p) {
            int u = p * 256 + tid;
            int cc = u >> 3, r8 = (u & 7) * 8;
            uint4 pk;
            pk.x = (unsigned)f2bf(tile[r8 + 0][cc]) | ((unsigned)f2bf(tile[r8 + 1][cc]) << 16);
            pk.y = (unsigned)f2bf(tile[r8 + 2][cc]) | ((unsigned)f2bf(tile[r8 + 3][cc]) << 16);
            pk.z = (unsigned)f2bf(tile[r8 + 4][cc]) | ((unsigned)f2bf(tile[r8 + 5][cc]) << 16);
            pk.w = (unsigned)f2bf(tile[r8 + 6][cc]) | ((unsigned)f2bf(tile[r8 + 7][cc]) << 16);
            *(uint4*)&outp[(size_t)(c0 + cc) * out_ld + out_off + r0 + r8] = pk;
        }
        return;
    }
    {   // pack_wdown: wdt[j][c] = wdown[e][c][r], j = e*16+r
        int idx = (b - 10584) * 256 + tid;
        int j = idx / 768, c = idx - j * 768;
        int e = j >> 4, r = j & 15;
        wdt[idx] = f2bf(wdn[((size_t)e * 768 + c) * 16 + r]);
    }
}

// ---- old MFMA GEMM (R12-proven), used only for GEMMd (EPI=1, TM=128) --------
template <int EPI, int TM>
__global__ void __launch_bounds__(TM * 2)
gemm_bt_kernel(const unsigned short* __restrict__ A, int lda,
               const unsigned short* __restrict__ Bt, int ldb,
               int kIters,
               const float* __restrict__ bias,
               unsigned short* __restrict__ apOut,
               float* __restrict__ fOut,
               const int* __restrict__ tki,
               const float* __restrict__ tkp) {
    constexpr int NT    = TM * 2;          // threads
    constexpr int ABUF  = TM * 32;         // elems per A buffer
    constexpr int BBUF  = 128 * 32;        // elems per B buffer
    __shared__ __align__(16) unsigned short As[2 * ABUF];
    __shared__ __align__(16) unsigned short Bs[2 * BBUF];

    const int bx = blockIdx.x, by = blockIdx.y;
    const int tid  = threadIdx.x;
    const int wave = tid >> 6;
    const int lane = tid & 63;
    const int m0 = by * TM;
    const int n0 = bx * 128;
    const int wm = (wave >> 1) * 64;
    const int wn = (wave & 1) * 64;
    const int row16 = lane & 15;
    const int quad  = lane >> 4;
    const int kch   = quad * 8;

    f32x4 acc[4][4] = {};

    const int r_s = tid >> 2;
    const int c_s = (tid & 3) * 8;
    const size_t aRow0 = (size_t)(m0 + r_s) * lda + c_s;
    const size_t aRow1 = aRow0 + (size_t)(NT / 4) * lda;
    const size_t bRow0 = (size_t)(n0 + r_s) * ldb + c_s;
    const size_t bRow1 = bRow0 + (size_t)64 * ldb;       // used only if TM==128
    unsigned short* asB0 = &As[(wave * 64) * 8];
    unsigned short* asB1 = &As[(NT + wave * 64) * 8];
    unsigned short* bsB0 = &Bs[(wave * 64) * 8];
    unsigned short* bsB1 = &Bs[(256 + wave * 64) * 8];

    {
        GLD(A + aRow0, asB0);
        GLD(A + aRow1, asB1);
        GLD(Bt + bRow0, bsB0);
        if (TM == 128) GLD(Bt + bRow1, bsB1);
    }

    for (int kt = 0; kt < kIters; ++kt) {
        __syncthreads();

        if (kt + 1 < kIters) {
            const int k1 = (kt + 1) * 32;
            const int pa = ((kt + 1) & 1) * ABUF;
            const int pb = ((kt + 1) & 1) * BBUF;
            GLD(A + aRow0 + k1, asB0 + pa);
            GLD(A + aRow1 + k1, asB1 + pa);
            GLD(Bt + bRow0 + k1, bsB0 + pb);
            if (TM == 128) GLD(Bt + bRow1 + k1, bsB1 + pb);
        }

        const int ca = (kt & 1) * ABUF;
        const int cb = (kt & 1) * BBUF;
        bf16x8 af[4], bfr[4];
        #pragma unroll
        for (int mi = 0; mi < 4; ++mi)
            af[mi] = *(const bf16x8*)&As[ca + (wm + mi * 16 + row16) * 32 + kch];
        #pragma unroll
        for (int ni = 0; ni < 4; ++ni)
            bfr[ni] = *(const bf16x8*)&Bs[cb + (wn + ni * 16 + row16) * 32 + kch];

        #pragma unroll
        for (int mi = 0; mi < 4; ++mi)
            #pragma unroll
            for (int ni = 0; ni < 4; ++ni)
                acc[mi][ni] = __builtin_amdgcn_mfma_f32_16x16x32_bf16(
                    af[mi], bfr[ni], acc[mi][ni], 0, 0, 0);
    }

    #pragma unroll
    for (int mi = 0; mi < 4; ++mi) {
        #pragma unroll
        for (int i = 0; i < 4; ++i) {
            const int m = m0 + wm + mi * 16 + quad * 4 + i;
            int i0 = 0, i1 = 0; float p0 = 0.f, p1 = 0.f;
            if (EPI == 1) {
                i0 = tki[m * 2]; i1 = tki[m * 2 + 1];
                p0 = tkp[m * 2]; p1 = tkp[m * 2 + 1];
            }
            #pragma unroll
            for (int ni = 0; ni < 4; ++ni) {
                const int ncol = n0 + wn + ni * 16 + row16;
                float v = acc[mi][ni][i];
                if (EPI == 0) {
                    v = gelu_fast(v + bias[ncol]);
                    apOut[(size_t)m * KBIG + ncol] = f2bf(v);
                } else if (EPI == 1) {
                    const int e = ncol >> 4;
                    float wt = (i0 == e ? p0 : 0.f) + (i1 == e ? p1 : 0.f);
                    v = gelu_fast(v) * wt;
                    apOut[(size_t)m * KBIG + 3072 + ncol] = f2bf(v);
                } else {
                    fOut[(size_t)m * CDIM + ncol] = v + bias[ncol];
                }
            }
        }
    }
}

// ---- 4-phase 128 x (32*NFRAG) BK=32 GEMM, 4 waves, multi-block/CU -----------
// 256 thr = 4 waves (2M x 2N); per-wave C = 64 x (16*NFRAG), acc[4][NFRAG].
// LDS: A [2]x8KB at 0, B [2]x(NFRAG*2KB) at +16KB. K-tile = 32 cols -> 64B
// rows. 2-bit swizzle byte ^= ((byte>>7)&3)<<4 on BOTH sides; frag reads at
// bank-group 4(r&1)+(q^((r>>1)&3)) -> distinct per 8-lane cohort (model
// consistent with the measured 128B-row/3-bit result).
// Per iteration (2 k-tiles, 4 phases; BCH = NFRAG/2 B-chunks of 4KB):
//   ph0 (t,P0):  issue A(t+1)->a1 [2]
//   ph1 (t,P1):  issue B(t+2)->b0 [BCH]   TAIL vmcnt(BCH)
//   ph2 (t+1,P0): issue A(t+2)->a0 [2]
//   ph3 (t+1,P1): issue B(t+3)->b1 [BCH]  TAIL vmcnt(BCH)
// vmcnt(BCH) leaves only the newest B-tile outstanding -> the next phase's
// A+B are forced landed; never drains to 0 in the main loop. Overwrites are
// >=1 full barrier after the last ds_read of the old contents.

template <int NFRAG, int P, bool TAILV, class Issue>
__device__ __forceinline__ void phase5(
        const char* lds, int aO, int bO,
        f32x4 (&acc)[4][NFRAG], bf16x8 (&bfr)[NFRAG], Issue issue) {
    bf16x8 af[2];
    af[0] = *(const bf16x8*)(lds + aO + (2 * P + 0) * 1024);
    af[1] = *(const bf16x8*)(lds + aO + (2 * P + 1) * 1024);
    if (P == 0) {
        #pragma unroll
        for (int nf = 0; nf < NFRAG; ++nf)
            bfr[nf] = *(const bf16x8*)(lds + bO + nf * 1024);
    }
    issue();
    __builtin_amdgcn_s_barrier();
    asm volatile("s_waitcnt lgkmcnt(0)" ::: "memory");
    __builtin_amdgcn_sched_barrier(0);
    __builtin_amdgcn_s_setprio(1);
    #pragma unroll
    for (int f = 0; f < 2; ++f)
        #pragma unroll
        for (int nf = 0; nf < NFRAG; ++nf)
            acc[2 * P + f][nf] = __builtin_amdgcn_mfma_f32_16x16x32_bf16(
                af[f], bfr[nf], acc[2 * P + f][nf], 0, 0, 0);
    __builtin_amdgcn_s_setprio(0);
    if (TAILV) {
        if constexpr (NFRAG == 6) asm volatile("s_waitcnt vmcnt(3)" ::: "memory");
        else                      asm volatile("s_waitcnt vmcnt(2)" ::: "memory");
    }
    __builtin_amdgcn_s_barrier();
    __builtin_amdgcn_sched_barrier(0);
}

// EPI 0: gelu(acc + bias[n]) -> bf16 apOut[m*3200 + n]   (GEMM1)
// EPI 2: acc + bias[n]       -> f32  fOut[m*768 + n]     (GEMM2)
template <int EPI, int NFRAG, int NBX, int OCC>
__global__ void __launch_bounds__(256, OCC)
gemm5_kernel(const unsigned short* __restrict__ A, int lda,
             const unsigned short* __restrict__ Bt, int ldb,
             int kTiles, const float* __restrict__ bias,
             unsigned short* __restrict__ apOut, float* __restrict__ fOut) {
    constexpr int BBYTES = NFRAG * 2048;         // per B buffer (BN*32*2B)
    constexpr int BCH    = NFRAG / 2;            // B GLD chunks (4KB each)
    __shared__ __align__(1024) char ldsraw[16384 + 2 * BBYTES];
    char* ldsA = ldsraw;                         // [2] x 8 KB
    char* ldsB = ldsraw + 16384;                 // [2] x BBYTES

    // bijective XCD swizzle (m204), bx-fast order: each XCD's contiguous
    // wgid chunk shares A row-panels (L2 dedup).
    const int nwg  = gridDim.x;
    const int q    = nwg >> 3, r = nwg & 7;
    const int orig = blockIdx.x;
    const int xcd  = orig & 7, within = orig >> 3;
    const int wgid = (xcd < r ? xcd * (q + 1) : r * (q + 1) + (xcd - r) * q) + within;
    const int bx = wgid % NBX, by = wgid / NBX;

    const int tid  = threadIdx.x;
    const int wave = tid >> 6;
    const int lane = tid & 63;
    const int m0 = by * 128;
    const int n0 = bx * (NFRAG * 32);
    const int row16 = lane & 15;
    const int quad  = lane >> 4;
    const int wm = (wave >> 1) * 64;             // 2 M-waves
    const int wn = (wave & 1) * (NFRAG * 16);    // 2 N-waves
    // ds_read fragment bases: 64B rows; bits4-5 ^= (row>>1)&3 (row16-only,
    // since wm/wn/mi*16/nf*16 contribute 0 to (r>>1)&3).
    const int sw2 = (row16 >> 1) & 3;
    const int aB = ((wm + row16) << 6) + ((quad ^ sw2) << 4);
    const int bB = 16384 + ((wn + row16) << 6) + ((quad ^ sw2) << 4);

    // staging: dest linear in tid (4KB chunks, chunk bases 4096-aligned so
    // the involution acts per-chunk); source pre-swizzled with the same map.
    const int d  = tid << 4;
    const int s  = d ^ (((d >> 7) & 3) << 4);
    const int sr = s >> 6;                 // source row 0..63 per chunk
    const int sc = (s & 63) >> 1;          // source col (ushort units)
    const unsigned short* aSrc = A + (size_t)(m0 + sr) * lda + sc;
    const unsigned short* bSrc = Bt + (size_t)(n0 + sr) * ldb + sc;
    const size_t aStep = (size_t)64 * lda; // 64 rows (ushort units)
    const size_t bStep = (size_t)64 * ldb;
    const int ldsW = wave << 10;

    auto issueA = [&](int b, int tk) {           // 128 rows = 2 GLD
        const unsigned short* sp = aSrc + tk * 32;
        char* dp = ldsA + b * 8192 + ldsW;
        GLD(sp, dp);
        GLD(sp + aStep, dp + 4096);
    };
    auto issueB = [&](int b, int tk) {           // NFRAG*32 rows = BCH GLD
        const unsigned short* sp = bSrc + tk * 32;
        char* dp = ldsB + b * BBYTES + ldsW;
        #pragma unroll
        for (int c = 0; c < BCH; ++c)
            GLD(sp + (size_t)c * bStep, dp + c * 4096);
    };

    f32x4 acc[4][NFRAG] = {};

    // prologue: B(0)->b0, A(0)->a0, B(1)->b1; leave B(1)'s BCH outstanding
    issueB(0, 0);
    issueA(0, 0);
    issueB(1, 1);
    if constexpr (NFRAG == 6) asm volatile("s_waitcnt vmcnt(3)" ::: "memory");
    else                      asm volatile("s_waitcnt vmcnt(2)" ::: "memory");
    __builtin_amdgcn_s_barrier();
    __builtin_amdgcn_sched_barrier(0);

    const int nIter = kTiles >> 1;
    for (int it = 0; it < nIter; ++it) {
        const int t  = it * 2;
        const int t2 = (t + 2 < kTiles) ? t + 2 : 0;   // clamped (harmless re-stage)
        const int t3 = (t + 3 < kTiles) ? t + 3 : 0;
        bf16x8 bfr[NFRAG];
        phase5<NFRAG, 0, false>(ldsraw, aB, bB, acc, bfr, [&]{ issueA(1, t + 1); });
        phase5<NFRAG, 1, true >(ldsraw, aB, bB, acc, bfr, [&]{ issueB(0, t2); });
        phase5<NFRAG, 0, false>(ldsraw, aB + 8192, bB + BBYTES, acc, bfr, [&]{ issueA(0, t2); });
        phase5<NFRAG, 1, true >(ldsraw, aB + 8192, bB + BBYTES, acc, bfr, [&]{ issueB(1, t3); });
    }
    asm volatile("s_waitcnt vmcnt(0)" ::: "memory");

    // epilogue: C/D layout col = row16 + nf*16, row = quad*4 + i (+ mi*16)
    float bv[NFRAG];
    #pragma unroll
    for (int nf = 0; nf < NFRAG; ++nf) bv[nf] = bias[n0 + wn + nf * 16 + row16];
    #pragma unroll
    for (int mi = 0; mi < 4; ++mi) {
        #pragma unroll
        for (int i = 0; i < 4; ++i) {
            const int m = m0 + wm + mi * 16 + quad * 4 + i;
            #pragma unroll
            for (int nf = 0; nf < NFRAG; ++nf) {
                const int col = n0 + wn + nf * 16 + row16;
                float v = acc[mi][nf][i] + bv[nf];
                if (EPI == 0) apOut[(size_t)m * KBIG + col] = f2bf(gelu_fast(v));
                else          fOut[(size_t)m * CDIM + col] = v;
            }
        }
    }
}

// ---------------- launch ----------------

extern "C" void kernel_launch(void* const* d_in, const int* in_sizes, int n_in,
                              void* d_out, int out_size, void* d_ws, size_t ws_size,
                              hipStream_t stream) {
    const float* x   = (const float*)d_in[0];
    const float* tkp = (const float*)d_in[1];
    const int*   tki = (const int*)d_in[2];
    const float* w1  = (const float*)d_in[3];
    const float* b1  = (const float*)d_in[4];
    const float* w2  = (const float*)d_in[5];
    const float* b2  = (const float*)d_in[6];
    const float* wdn = (const float*)d_in[7];
    const float* wup = (const float*)d_in[8];
    float* out = (float*)d_out;

    unsigned short* xb  = (unsigned short*)d_ws;
    unsigned short* w1t = xb  + (size_t)NTOK * CDIM;      // 3072 x 768
    unsigned short* B2t = w1t + (size_t)HIDDIM * CDIM;    // 768 x 3200
    unsigned short* wdt = B2t + (size_t)CDIM * KBIG;      // 128 x 768
    unsigned short* Ap  = wdt + (size_t)128 * CDIM;       // 12544 x 3200

    prep_kernel<<<dim3(10968), 256, 0, stream>>>(x, w1, w2, wup, wdn,
                                                 xb, w1t, B2t, wdt);

    // GEMMd: sd -> Ap[:, 3072:3200] ; 98 blocks, proven R12 kernel
    gemm_bt_kernel<1, 128><<<dim3(1, NTOK / 128), 256, 0, stream>>>(
        xb, CDIM, wdt, CDIM, CDIM / 32, nullptr, Ap, nullptr, tki, tkp);
    // GEMM1: h -> Ap[:, 0:3072] ; 128x192, BK=32, 3 blocks/CU, 1568 blocks
    gemm5_kernel<0, 6, HIDDIM / 192, 3>
        <<<dim3((HIDDIM / 192) * (NTOK / 128)), 256, 0, stream>>>(
        xb, CDIM, w1t, CDIM, CDIM / 32, b1, Ap, nullptr);
    // GEMM2: out = Ap @ B2t^T + b2 ; 128x128, BK=32, 4 blocks/CU, 588 blocks
    gemm5_kernel<2, 4, CDIM / 128, 4>
        <<<dim3((CDIM / 128) * (NTOK / 128)), 256, 0, stream>>>(
        Ap, KBIG, B2t, KBIG, KBIG / 32, b2, nullptr, out);
}

// Round 7
// 252.547 us; speedup vs baseline: 1.1574x; 1.1574x over previous
//
#include <hip/hip_runtime.h>
#include <hip/hip_bf16.h>
#include <math.h>

// ConvNeXt MLP + parallel MoE-LoRA, fp32 in/out, bf16-tolerance harness.
// B,H,W,C = 64,14,14,768 ; N_tok = 12544 = 98*128 ; HID = 3072 ; E=8,K=2,R=16.
//
//   h  = gelu(x @ w1 + b1)                GEMM1  [12544,768]x[768,3072]
//   sd = wt * gelu(x @ wdown)             GEMMd  [12544,768]x[768,128]
//   out = [h | sd] @ [w2 ; wup] + b2      GEMM2  [12544,3200]x[3200,768]
//
// R19: R18 post-mortem: BK=32 doubled the phase/barrier count per K-column
// (fixed per-phase costs dominate) -> MfmaUtil 32->24.5, GEMM1 97us. REVERT
// to R17's gemm4 (128x192 BK=64, 80KB LDS, 2 blocks/CU, 4-phase counted
// vmcnt(3), 3-bit both-sides swizzle, XCD-bijective grid swizzle). Rule:
// never reduce MFMA-per-barrier.
// New in R19: GEMMd merged into GEMM1 as 98 TAIL blocks (orig >= 1568).
// Block-uniform branch into a fully SEPARATE loop (own 128x128 tile from
// wdt, vmcnt(2) schedule, EPI1 epilogue) - not R13's runtime-B-in-shared-
// loop fusion. LoRA blocks dispatch last -> fill GEMM1's scheduling tail;
// the standalone 98-block latency-bound GEMMd launch (+gap) disappears.

#define NTOK   12544
#define CDIM   768
#define HIDDIM 3072
#define KBIG   3200

typedef __attribute__((ext_vector_type(8))) short bf16x8;
typedef __attribute__((ext_vector_type(4))) float f32x4;

#define GLOBAL_AS(p) ((const __attribute__((address_space(1))) void*)(p))
#define LDS_AS(p)    ((__attribute__((address_space(3))) void*)(p))
#define GLD(src, dst) __builtin_amdgcn_global_load_lds(GLOBAL_AS(src), LDS_AS(dst), 16, 0, 0)

__device__ inline unsigned short f2bf(float f) {
    unsigned int x = __float_as_uint(f);
    x += 0x7fffu + ((x >> 16) & 1u);   // RNE
    return (unsigned short)(x >> 16);
}

// tanh-form GELU, branch-free; max |err| ~4.3e-4 vs exact erf form.
__device__ inline float gelu_fast(float x) {
    float x3 = x * x * x;
    float u2 = 1.5957691216057308f * x + 0.07135481627260025f * x3;
    float e = __expf(-u2);
    return x * __builtin_amdgcn_rcpf(1.0f + e);
}

// ---------------- fused prep: cast_x + 3 transposes (64x64) + pack_wdown -------
__global__ void __launch_bounds__(256) prep_kernel(
        const float* __restrict__ x, const float* __restrict__ w1,
        const float* __restrict__ w2, const float* __restrict__ wup,
        const float* __restrict__ wdn,
        unsigned short* __restrict__ xb, unsigned short* __restrict__ w1t,
        unsigned short* __restrict__ B2t, unsigned short* __restrict__ wdt) {
    __shared__ float tile[64][65];
    const int b = blockIdx.x, tid = threadIdx.x;
    if (b < 9408) {                      // cast x -> bf16, float4->ushort4
        int i = b * 256 + tid;
        float4 v = ((const float4*)x)[i];
        ushort4 o;
        o.x = f2bf(v.x); o.y = f2bf(v.y); o.z = f2bf(v.z); o.w = f2bf(v.w);
        ((ushort4*)xb)[i] = o;
        return;
    }
    if (b < 10584) {                     // 64x64 transpose tiles
        const float* in; unsigned short* outp; int Ccols, out_ld, out_off, bx, by;
        if (b < 9984)       { int t = b - 9408;  in = w1;  outp = w1t; Ccols = 3072; out_ld = 768;  out_off = 0;    bx = t % 48; by = t / 48; }
        else if (b < 10560) { int t = b - 9984;  in = w2;  outp = B2t; Ccols = 768;  out_ld = 3200; out_off = 0;    bx = t % 12; by = t / 12; }
        else                { int t = b - 10560; in = wup; outp = B2t; Ccols = 768;  out_ld = 3200; out_off = 3072; bx = t % 12; by = t / 12; }
        const int c0 = bx * 64, r0 = by * 64;
        #pragma unroll
        for (int p = 0; p < 4; ++p) {
            int idx = p * 256 + tid;
            int r = idx >> 4, c4 = (idx & 15) * 4;
            float4 v = *(const float4*)&in[(size_t)(r0 + r) * Ccols + c0 + c4];
            tile[r][c4 + 0] = v.x; tile[r][c4 + 1] = v.y;
            tile[r][c4 + 2] = v.z; tile[r][c4 + 3] = v.w;
        }
        __syncthreads();
        #pragma unroll
        for (int p = 0; p < 2; ++p) {
            int u = p * 256 + tid;
            int cc = u >> 3, r8 = (u & 7) * 8;
            uint4 pk;
            pk.x = (unsigned)f2bf(tile[r8 + 0][cc]) | ((unsigned)f2bf(tile[r8 + 1][cc]) << 16);
            pk.y = (unsigned)f2bf(tile[r8 + 2][cc]) | ((unsigned)f2bf(tile[r8 + 3][cc]) << 16);
            pk.z = (unsigned)f2bf(tile[r8 + 4][cc]) | ((unsigned)f2bf(tile[r8 + 5][cc]) << 16);
            pk.w = (unsigned)f2bf(tile[r8 + 6][cc]) | ((unsigned)f2bf(tile[r8 + 7][cc]) << 16);
            *(uint4*)&outp[(size_t)(c0 + cc) * out_ld + out_off + r0 + r8] = pk;
        }
        return;
    }
    {   // pack_wdown: wdt[j][c] = wdown[e][c][r], j = e*16+r
        int idx = (b - 10584) * 256 + tid;
        int j = idx / 768, c = idx - j * 768;
        int e = j >> 4, r = j & 15;
        wdt[idx] = f2bf(wdn[((size_t)e * 768 + c) * 16 + r]);
    }
}

// ---- 4-phase BK=64 GEMM phase (R17-proven), NFRAG-generalized --------------
// Per phase: ds_read frags -> issue prefetch -> barrier -> lgkmcnt(0) ->
// setprio(1) MFMA cluster setprio(0) -> [tail vmcnt(VMN)] -> barrier.
// Tail vmcnt(VMN) leaves only the newest B-tile (VMN GLDs) outstanding ->
// the next phase's A+B are forced landed; never drains to 0 in the loop.
template <int NFRAG, int P, bool TAILV, int VMN, class Issue>
__device__ __forceinline__ void phase4n(
        const char* lds, int aO0, int aO1, int bO0, int bO1,
        f32x4 (&acc)[4][NFRAG], bf16x8 (&bfr)[NFRAG][2], Issue issue) {
    bf16x8 af[2][2];
    #pragma unroll
    for (int f = 0; f < 2; ++f) {
        af[f][0] = *(const bf16x8*)(lds + aO0 + (2 * P + f) * 2048);
        af[f][1] = *(const bf16x8*)(lds + aO1 + (2 * P + f) * 2048);
    }
    if (P == 0) {
        #pragma unroll
        for (int nf = 0; nf < NFRAG; ++nf) {
            bfr[nf][0] = *(const bf16x8*)(lds + bO0 + nf * 2048);
            bfr[nf][1] = *(const bf16x8*)(lds + bO1 + nf * 2048);
        }
    }
    issue();
    __builtin_amdgcn_s_barrier();
    asm volatile("s_waitcnt lgkmcnt(0)" ::: "memory");
    __builtin_amdgcn_sched_barrier(0);
    __builtin_amdgcn_s_setprio(1);
    #pragma unroll
    for (int f = 0; f < 2; ++f)
        #pragma unroll
        for (int nf = 0; nf < NFRAG; ++nf)
            #pragma unroll
            for (int k = 0; k < 2; ++k)
                acc[2 * P + f][nf] = __builtin_amdgcn_mfma_f32_16x16x32_bf16(
                    af[f][k], bfr[nf][k], acc[2 * P + f][nf], 0, 0, 0);
    __builtin_amdgcn_s_setprio(0);
    if (TAILV) {
        if constexpr (VMN == 3) asm volatile("s_waitcnt vmcnt(3)" ::: "memory");
        else                    asm volatile("s_waitcnt vmcnt(2)" ::: "memory");
    }
    __builtin_amdgcn_s_barrier();
    __builtin_amdgcn_sched_barrier(0);
}

// ---- 128x192 BK=64, 80KB LDS, 2 blocks/CU, 8 waves (2M x 4N) ----------------
// Main path identical to R17. If LORA: blocks orig >= MAIN run a separate
// 128x128 LoRA-GEMM (A=xb shared, B=Bt2=wdt ld 768) with EPI1 epilogue
// wt[m, col>>4] * gelu(acc) -> bf16 Ap[m*3200 + 3072 + col].
// EPI 0: gelu(acc + bias[n]) -> bf16 apOut[m*3200 + n]   (GEMM1)
// EPI 2: acc + bias[n]       -> f32  fOut[m*768 + n]     (GEMM2)
template <int EPI, int NBX, bool LORA>
__global__ void __launch_bounds__(512, 4)
gemm4_kernel(const unsigned short* __restrict__ A, int lda,
             const unsigned short* __restrict__ Bt, int ldb,
             int kTiles, const float* __restrict__ bias,
             unsigned short* __restrict__ apOut, float* __restrict__ fOut,
             const int* __restrict__ tki, const float* __restrict__ tkp,
             const unsigned short* __restrict__ Bt2) {
    __shared__ __align__(1024) char ldsraw[81920];     // 80 KiB -> 2 blocks/CU
    char* ldsA = ldsraw;                                // [2] x 16 KB
    char* ldsB = ldsraw + 32768;                        // [2] x 24 KB (16 KB lora)

    constexpr int MAIN = NBX * (NTOK / 128);            // main-grid blocks (%8==0)
    const int orig = blockIdx.x;

    const int tid  = threadIdx.x;
    const int wave = tid >> 6;
    const int lane = tid & 63;
    const int row16 = lane & 15;
    const int quad  = lane >> 4;
    const int wm = (wave >> 2) << 6;      // 0 / 64
    const int swz = (row16 & 7) << 4;
    const int aFB = ((wm + row16) << 7) + (quad << 4);
    const int aX0 = (aFB ^ swz), aX1 = ((aFB + 64) ^ swz);

    // staging decomposition (shared): dest linear in tid; source pre-swizzled
    // with the same 3-bit involution so LDS content is swizzle-stored.
    const int d  = tid << 4;
    const int s  = d ^ (((d >> 7) & 7) << 4);
    const int sr = s >> 7;                // source row 0..63 (per 8KB unit)
    const int sc = (s & 127) >> 1;        // source col elem (16B chunk)
    const int ldsW = wave << 10;

    if constexpr (LORA) {
        if (orig >= MAIN) {
            // ---------------- LoRA tail path: 128 x 128, K = kTiles*64 ------
            const int m0 = (orig - MAIN) * 128;
            const int wn = (wave & 3) << 5;            // 0/32/64/96
            const int bFB = ((wn + row16) << 7) + (quad << 4);
            const int bX0 = (bFB ^ swz) + 32768, bX1 = ((bFB + 64) ^ swz) + 32768;
            const char* aSrc = (const char*)(A + (size_t)(m0 + sr) * lda + sc);
            const char* bSrc = (const char*)(Bt2 + (size_t)sr * CDIM + sc);
            const size_t aStep = (size_t)64 * lda * 2;
            const size_t bStep = (size_t)64 * CDIM * 2;
            auto issueA = [&](int b, int tk) {         // 128 rows = 2 GLD
                const char* sp = aSrc + (size_t)tk * 128;
                char* dp = ldsA + b * 16384 + ldsW;
                GLD(sp, dp);
                GLD(sp + aStep, dp + 8192);
            };
            auto issueB = [&](int b, int tk) {         // 128 rows = 2 GLD
                const char* sp = bSrc + (size_t)tk * 128;
                char* dp = ldsB + b * 16384 + ldsW;
                GLD(sp, dp);
                GLD(sp + bStep, dp + 8192);
            };
            f32x4 acc[4][2] = {};
            issueB(0, 0); issueA(0, 0); issueB(1, 1);
            asm volatile("s_waitcnt vmcnt(2)" ::: "memory");
            __builtin_amdgcn_s_barrier();
            __builtin_amdgcn_sched_barrier(0);
            const int nIter = kTiles >> 1;
            for (int it = 0; it < nIter; ++it) {
                const int t  = it * 2;
                const int t2 = (t + 2 < kTiles) ? t + 2 : 0;
                const int t3 = (t + 3 < kTiles) ? t + 3 : 0;
                bf16x8 bfr[2][2];
                phase4n<2, 0, false, 2>(ldsraw, aX0, aX1, bX0, bX1, acc, bfr,
                                        [&]{ issueA(1, t + 1); });
                phase4n<2, 1, true , 2>(ldsraw, aX0, aX1, bX0, bX1, acc, bfr,
                                        [&]{ issueB(0, t2); });
                phase4n<2, 0, false, 2>(ldsraw, aX0 + 16384, aX1 + 16384, bX0 + 16384, bX1 + 16384,
                                        acc, bfr, [&]{ issueA(0, t2); });
                phase4n<2, 1, true , 2>(ldsraw, aX0 + 16384, aX1 + 16384, bX0 + 16384, bX1 + 16384,
                                        acc, bfr, [&]{ issueB(1, t3); });
            }
            asm volatile("s_waitcnt vmcnt(0)" ::: "memory");
            #pragma unroll
            for (int mi = 0; mi < 4; ++mi) {
                #pragma unroll
                for (int i = 0; i < 4; ++i) {
                    const int m = m0 + wm + mi * 16 + quad * 4 + i;
                    const int i0 = tki[m * 2], i1 = tki[m * 2 + 1];
                    const float p0 = tkp[m * 2], p1 = tkp[m * 2 + 1];
                    #pragma unroll
                    for (int nf = 0; nf < 2; ++nf) {
                        const int col = wn + nf * 16 + row16;
                        const int e = col >> 4;
                        float wt = (i0 == e ? p0 : 0.f) + (i1 == e ? p1 : 0.f);
                        apOut[(size_t)m * KBIG + 3072 + col] =
                            f2bf(gelu_fast(acc[mi][nf][i]) * wt);
                    }
                }
            }
            return;
        }
    }

    // ---------------- main path (R17-exact) ---------------------------------
    // bijective XCD swizzle (MAIN%8==0), bx-fast: each XCD's contiguous wgid
    // chunk shares A row-panels (L2 dedup).
    constexpr int qq = MAIN / 8;
    const int xcd = orig & 7, within = orig >> 3;
    const int wgid = xcd * qq + within;
    const int bx = wgid % NBX, by = wgid / NBX;

    const int m0 = by * 128;
    const int n0 = bx * 192;
    const int wn = (wave & 3) * 48;       // 0 / 48 / 96 / 144
    const int bFB = ((wn + row16) << 7) + (quad << 4);
    const int bX0 = (bFB ^ swz) + 32768, bX1 = ((bFB + 64) ^ swz) + 32768;

    const char* aSrc = (const char*)(A + (size_t)(m0 + sr) * lda + sc);
    const char* bSrc = (const char*)(Bt + (size_t)(n0 + sr) * ldb + sc);
    const size_t aStep = (size_t)64 * lda * 2;   // 64 rows, bytes
    const size_t bStep = (size_t)64 * ldb * 2;

    auto issueA = [&](int b, int tk) {           // 128 rows = 2 GLD
        const char* sp = aSrc + (size_t)tk * 128;
        char* dp = ldsA + b * 16384 + ldsW;
        GLD(sp, dp);
        GLD(sp + aStep, dp + 8192);
    };
    auto issueB = [&](int b, int tk) {           // 192 rows = 3 GLD
        const char* sp = bSrc + (size_t)tk * 128;
        char* dp = ldsB + b * 24576 + ldsW;
        GLD(sp, dp);
        GLD(sp + bStep, dp + 8192);
        GLD(sp + 2 * bStep, dp + 16384);
    };

    f32x4 acc[4][3] = {};

    // prologue: B(0)->b0, A(0)->a0, B(1)->b1; leave B(1)'s 3 outstanding
    issueB(0, 0);
    issueA(0, 0);
    issueB(1, 1);
    asm volatile("s_waitcnt vmcnt(3)" ::: "memory");
    __builtin_amdgcn_s_barrier();
    __builtin_amdgcn_sched_barrier(0);

    const int nIter = kTiles >> 1;
    for (int it = 0; it < nIter; ++it) {
        const int t  = it * 2;
        const int t2 = (t + 2 < kTiles) ? t + 2 : 0;   // clamped (harmless re-stage)
        const int t3 = (t + 3 < kTiles) ? t + 3 : 0;
        bf16x8 bfr[3][2];
        phase4n<3, 0, false, 3>(ldsraw, aX0, aX1, bX0, bX1, acc, bfr,
                                [&]{ issueA(1, t + 1); });
        phase4n<3, 1, true , 3>(ldsraw, aX0, aX1, bX0, bX1, acc, bfr,
                                [&]{ issueB(0, t2); });
        phase4n<3, 0, false, 3>(ldsraw, aX0 + 16384, aX1 + 16384, bX0 + 24576, bX1 + 24576,
                                acc, bfr, [&]{ issueA(0, t2); });
        phase4n<3, 1, true , 3>(ldsraw, aX0 + 16384, aX1 + 16384, bX0 + 24576, bX1 + 24576,
                                acc, bfr, [&]{ issueB(1, t3); });
    }
    asm volatile("s_waitcnt vmcnt(0)" ::: "memory");

    // epilogue: C/D layout col = row16 + nf*16, row = quad*4 + i (+ mi*16)
    float bv[3];
    #pragma unroll
    for (int nf = 0; nf < 3; ++nf) bv[nf] = bias[n0 + wn + nf * 16 + row16];
    #pragma unroll
    for (int mi = 0; mi < 4; ++mi) {
        #pragma unroll
        for (int i = 0; i < 4; ++i) {
            const int m = m0 + wm + mi * 16 + quad * 4 + i;
            #pragma unroll
            for (int nf = 0; nf < 3; ++nf) {
                const int col = n0 + wn + nf * 16 + row16;
                float v = acc[mi][nf][i] + bv[nf];
                if (EPI == 0) apOut[(size_t)m * KBIG + col] = f2bf(gelu_fast(v));
                else          fOut[(size_t)m * CDIM + col] = v;
            }
        }
    }
}

// ---------------- launch ----------------

extern "C" void kernel_launch(void* const* d_in, const int* in_sizes, int n_in,
                              void* d_out, int out_size, void* d_ws, size_t ws_size,
                              hipStream_t stream) {
    const float* x   = (const float*)d_in[0];
    const float* tkp = (const float*)d_in[1];
    const int*   tki = (const int*)d_in[2];
    const float* w1  = (const float*)d_in[3];
    const float* b1  = (const float*)d_in[4];
    const float* w2  = (const float*)d_in[5];
    const float* b2  = (const float*)d_in[6];
    const float* wdn = (const float*)d_in[7];
    const float* wup = (const float*)d_in[8];
    float* out = (float*)d_out;

    unsigned short* xb  = (unsigned short*)d_ws;
    unsigned short* w1t = xb  + (size_t)NTOK * CDIM;      // 3072 x 768
    unsigned short* B2t = w1t + (size_t)HIDDIM * CDIM;    // 768 x 3200
    unsigned short* wdt = B2t + (size_t)CDIM * KBIG;      // 128 x 768
    unsigned short* Ap  = wdt + (size_t)128 * CDIM;       // 12544 x 3200

    prep_kernel<<<dim3(10968), 256, 0, stream>>>(x, w1, w2, wup, wdn,
                                                 xb, w1t, B2t, wdt);

    // GEMM1 + GEMMd fused grid: 1568 main blocks (128x192) + 98 LoRA tail
    // blocks (128x128, dispatched last -> fill the scheduling tail).
    gemm4_kernel<0, HIDDIM / 192, true>
        <<<dim3((HIDDIM / 192 + 1) * (NTOK / 128)), 512, 0, stream>>>(
        xb, CDIM, w1t, CDIM, CDIM / 64, b1, Ap, nullptr, tki, tkp, wdt);
    // GEMM2: out = Ap @ B2t^T + b2 ; 128x192, 2 blocks/CU, 392 blocks swizzled
    gemm4_kernel<2, CDIM / 192, false>
        <<<dim3((CDIM / 192) * (NTOK / 128)), 512, 0, stream>>>(
        Ap, KBIG, B2t, KBIG, KBIG / 64, b2, nullptr, out, nullptr, nullptr, nullptr);
}